// Round 1
// baseline (424.106 us; speedup 1.0000x reference)
//
#include <hip/hip_runtime.h>
#include <math.h>

#define N 8192
#define IN_F 256
#define OUT_F 128
#define ALPHA 0.2f

#define SEG 8              // j-segments (split-softmax); 512 blocks = 2/CU
#define JSEG (N / SEG)     // 1024 columns per wave
#define CHN (JSEG / 32)    // 32 chunks of 32 j per wave

typedef _Float16 f16;
typedef __attribute__((ext_vector_type(4))) float f32x4;
typedef __attribute__((ext_vector_type(8))) _Float16 f16x8;
typedef __attribute__((ext_vector_type(4))) _Float16 f16x4;
typedef __attribute__((ext_vector_type(4))) int i32x4;

// ---------------- Kernel 0: WT[f][k] = (f16) W[k][f] ----------------
__global__ __launch_bounds__(256) void k_prep(const float* __restrict__ W,
                                              f16* __restrict__ WT) {
    int idx = blockIdx.x * 256 + threadIdx.x;   // 128*256 = 32768 elements
    int f = idx >> 8;
    int k = idx & 255;
    WT[idx] = (f16)W[k * OUT_F + f];
}

// ---------------- Kernel 1: Wh = h@W via MFMA; emit WhT(f16), src, dst ----------------
// Block: 256 threads (4 waves), 32 rows. Wave wv handles f-slice [32wv, 32wv+32).
#define HS 280   // f16 row stride for hA: 560 B = 140 dw === 12 (mod 32) -> conflict-optimal b128
__global__ __launch_bounds__(256) void k_wh(const float* __restrict__ h,
                                            const f16* __restrict__ WT,   // [128][256]
                                            const float* __restrict__ a,
                                            f16* __restrict__ WhT,        // [128][8192]
                                            float* __restrict__ src,
                                            float* __restrict__ dst) {
    __shared__ __align__(16) f16 hA[32][HS];       // 17.9 KB
    __shared__ __align__(16) f16 outT[128][40];    // [col][row], 80 B rows, 10 KB
    __shared__ float sred[4][32], dred[4][32];

    const int t = threadIdx.x;
    const int i0 = blockIdx.x * 32;
    const int wv = t >> 6, l = t & 63, ln = l & 15, lq = l >> 4;

    // stage h tile (32 x 256 fp32) -> f16 LDS
    {
        const float4* hg = (const float4*)(h + (size_t)i0 * IN_F);
#pragma unroll
        for (int it = 0; it < 8; ++it) {
            int idx = t + it * 256;        // float4 index, 2048 total
            int r = idx >> 6;
            int c4 = (idx & 63) * 4;
            float4 v = hg[idx];
            f16x4 p = { (f16)v.x, (f16)v.y, (f16)v.z, (f16)v.w };
            *(f16x4*)&hA[r][c4] = p;
        }
    }
    __syncthreads();

    f32x4 acc00 = {0.f,0.f,0.f,0.f}, acc01 = {0.f,0.f,0.f,0.f};
    f32x4 acc10 = {0.f,0.f,0.f,0.f}, acc11 = {0.f,0.f,0.f,0.f};
    const int f0 = 32 * wv;

#pragma unroll
    for (int ks = 0; ks < 8; ++ks) {
        const int k0 = 32 * ks + 8 * lq;
        f16x8 a0 = *(const f16x8*)&hA[ln][k0];
        f16x8 a1 = *(const f16x8*)&hA[16 + ln][k0];
        f16x8 b0 = *(const f16x8*)(WT + (size_t)(f0 + ln) * IN_F + k0);
        f16x8 b1 = *(const f16x8*)(WT + (size_t)(f0 + 16 + ln) * IN_F + k0);
        acc00 = __builtin_amdgcn_mfma_f32_16x16x32_f16(a0, b0, acc00, 0, 0, 0);
        acc01 = __builtin_amdgcn_mfma_f32_16x16x32_f16(a0, b1, acc01, 0, 0, 0);
        acc10 = __builtin_amdgcn_mfma_f32_16x16x32_f16(a1, b0, acc10, 0, 0, 0);
        acc11 = __builtin_amdgcn_mfma_f32_16x16x32_f16(a1, b1, acc11, 0, 0, 0);
    }

    // epilogue: per-lane src/dst partials + outT staging
    const float a1c0 = a[f0 + ln],      a2c0 = a[128 + f0 + ln];
    const float a1c1 = a[f0 + 16 + ln], a2c1 = a[128 + f0 + 16 + ln];
    float sp[8], dp[8];
#pragma unroll
    for (int i = 0; i < 8; ++i) { sp[i] = 0.f; dp[i] = 0.f; }

#pragma unroll
    for (int hh = 0; hh < 2; ++hh) {
        f32x4 v0 = hh ? acc10 : acc00;   // ft=0
        f32x4 v1 = hh ? acc11 : acc01;   // ft=1
        f16x4 p0, p1;
#pragma unroll
        for (int rg = 0; rg < 4; ++rg) {
            sp[hh * 4 + rg] += v0[rg] * a1c0 + v1[rg] * a1c1;
            dp[hh * 4 + rg] += v0[rg] * a2c0 + v1[rg] * a2c1;
            p0[rg] = (f16)v0[rg];
            p1[rg] = (f16)v1[rg];
        }
        *(f16x4*)&outT[f0 + ln][16 * hh + 4 * lq] = p0;
        *(f16x4*)&outT[f0 + 16 + ln][16 * hh + 4 * lq] = p1;
    }
    // reduce over ln (16 lanes sharing lq)
#pragma unroll
    for (int i = 0; i < 8; ++i) {
        float s = sp[i], d = dp[i];
        s += __shfl_down(s, 8, 16); d += __shfl_down(d, 8, 16);
        s += __shfl_down(s, 4, 16); d += __shfl_down(d, 4, 16);
        s += __shfl_down(s, 2, 16); d += __shfl_down(d, 2, 16);
        s += __shfl_down(s, 1, 16); d += __shfl_down(d, 1, 16);
        if (ln == 0) {
            int row = 16 * (i >> 2) + 4 * lq + (i & 3);
            sred[wv][row] = s;
            dred[wv][row] = d;
        }
    }
    __syncthreads();
    if (t < 32) {
        src[i0 + t] = sred[0][t] + sred[1][t] + sred[2][t] + sred[3][t];
        dst[i0 + t] = dred[0][t] + dred[1][t] + dred[2][t] + dred[3][t];
    }
    // write WhT[col][i0..i0+31]
    {
        const int col = t & 127, g = t >> 7;
        f16x8 q0 = *(const f16x8*)&outT[col][16 * g];
        f16x8 q1 = *(const f16x8*)&outT[col][16 * g + 8];
        *(f16x8*)(WhT + (size_t)col * N + i0 + 16 * g) = q0;
        *(f16x8*)(WhT + (size_t)col * N + i0 + 16 * g + 8) = q1;
    }
}

// ---------------- Kernel 2: barrier-free flash attention partials ----------------
// Grid: 512 blocks = 64 row-groups x 8 j-segments; seg = bid%8 -> pins segment to one XCD.
// Block: 256 threads = 4 waves; each wave owns 32 rows x 1024 j. NO LDS, NO barriers.
// Lane (ln,lq) computes w[row][8 j] straight into its MFMA A-fragment registers.
// adj is nontemporal (don't evict the hot WhT slice from L2).
// Per chunk: issue B(c) -> compute w(c) (waits adj issued 2 chunks ago) ->
//            issue adj(c+2) -> 16 MFMA (vmcnt waits only B(c), never the HBM prefetch).
__global__ __launch_bounds__(256) void k_attn(const int* __restrict__ adj,
                                              const f16* __restrict__ WhT,
                                              const float* __restrict__ src,
                                              const float* __restrict__ dst,
                                              float* __restrict__ part,     // [SEG][N][OUT_F]
                                              float* __restrict__ lpPart) { // [SEG][N]
    const int t = threadIdx.x;
    const int wv = t >> 6, l = t & 63, ln = l & 15, lq = l >> 4;
    const int bid = blockIdx.x;
    const int s  = bid & (SEG - 1);
    const int rg = bid >> 3;
    const int R0 = rg * 128 + wv * 32;
    const int jb = s * JSEG;

    const float src0 = src[R0 + ln],      src1 = src[R0 + 16 + ln];
    const float csh0 = fabsf(src0) + 4.0f, csh1 = fabsf(src1) + 4.0f;

    const int*   __restrict__ ar0 = adj + (size_t)(R0 + ln) * N + jb + 8 * lq;
    const int*   __restrict__ ar1 = adj + (size_t)(R0 + 16 + ln) * N + jb + 8 * lq;
    const float* __restrict__ dp  = dst + jb + 8 * lq;
    const f16*   __restrict__ Bp  = WhT + (size_t)ln * N + jb + 8 * lq;

    f32x4 acc0[8], acc1[8];
#pragma unroll
    for (int i = 0; i < 8; ++i) {
        acc0[i] = (f32x4){0.f, 0.f, 0.f, 0.f};
        acc1[i] = (f32x4){0.f, 0.f, 0.f, 0.f};
    }
    float lp0 = 0.f, lp1 = 0.f;

    i32x4 aA00, aA01, aA10, aA11, aB00, aB01, aB10, aB11;
    f32x4 dA0, dA1, dB0, dB1;

#define ISSUE(c, A00, A01, A10, A11, D0, D1)                                   \
    {                                                                          \
        const int o = (c) * 32;                                                \
        A00 = __builtin_nontemporal_load((const i32x4*)(ar0 + o));             \
        A01 = __builtin_nontemporal_load((const i32x4*)(ar0 + o + 4));         \
        A10 = __builtin_nontemporal_load((const i32x4*)(ar1 + o));             \
        A11 = __builtin_nontemporal_load((const i32x4*)(ar1 + o + 4));         \
        D0  = *(const f32x4*)(dp + o);                                         \
        D1  = *(const f32x4*)(dp + o + 4);                                     \
    }

    // w computation: leaky_relu via 0.6*e + 0.4*|e| (2 VALU), exp with fixed shift
    auto cw = [&](const i32x4& A00, const i32x4& A01, const i32x4& A10, const i32x4& A11,
                  const f32x4& D0, const f32x4& D1, f16x8& w0, f16x8& w1) {
#pragma unroll
        for (int k = 0; k < 4; ++k) {
            float e, lk, v;
            e = src0 + D0[k]; lk = fmaf(0.4f, fabsf(e), 0.6f * e);
            v = A00[k] ? __expf(lk - csh0) : 0.f; lp0 += v; w0[k] = (f16)v;
            e = src0 + D1[k]; lk = fmaf(0.4f, fabsf(e), 0.6f * e);
            v = A01[k] ? __expf(lk - csh0) : 0.f; lp0 += v; w0[4 + k] = (f16)v;
            e = src1 + D0[k]; lk = fmaf(0.4f, fabsf(e), 0.6f * e);
            v = A10[k] ? __expf(lk - csh1) : 0.f; lp1 += v; w1[k] = (f16)v;
            e = src1 + D1[k]; lk = fmaf(0.4f, fabsf(e), 0.6f * e);
            v = A11[k] ? __expf(lk - csh1) : 0.f; lp1 += v; w1[4 + k] = (f16)v;
        }
    };

    ISSUE(0, aA00, aA01, aA10, aA11, dA0, dA1);
    ISSUE(1, aB00, aB01, aB10, aB11, dB0, dB1);

    for (int c = 0; c < CHN; c += 2) {
        {   // even chunk: data in set A
            const f16* bp = Bp + c * 32;
            f16x8 b[8];
#pragma unroll
            for (int ft = 0; ft < 8; ++ft)
                b[ft] = *(const f16x8*)(bp + (size_t)(16 * ft) * N);
            f16x8 w0, w1;
            cw(aA00, aA01, aA10, aA11, dA0, dA1, w0, w1);
            if (c + 2 < CHN) ISSUE(c + 2, aA00, aA01, aA10, aA11, dA0, dA1);
#pragma unroll
            for (int ft = 0; ft < 8; ++ft) {
                acc0[ft] = __builtin_amdgcn_mfma_f32_16x16x32_f16(w0, b[ft], acc0[ft], 0, 0, 0);
                acc1[ft] = __builtin_amdgcn_mfma_f32_16x16x32_f16(w1, b[ft], acc1[ft], 0, 0, 0);
            }
        }
        {   // odd chunk: data in set B
            const f16* bp = Bp + (c + 1) * 32;
            f16x8 b[8];
#pragma unroll
            for (int ft = 0; ft < 8; ++ft)
                b[ft] = *(const f16x8*)(bp + (size_t)(16 * ft) * N);
            f16x8 w0, w1;
            cw(aB00, aB01, aB10, aB11, dB0, dB1, w0, w1);
            if (c + 3 < CHN) ISSUE(c + 3, aB00, aB01, aB10, aB11, dB0, dB1);
#pragma unroll
            for (int ft = 0; ft < 8; ++ft) {
                acc0[ft] = __builtin_amdgcn_mfma_f32_16x16x32_f16(w0, b[ft], acc0[ft], 0, 0, 0);
                acc1[ft] = __builtin_amdgcn_mfma_f32_16x16x32_f16(w1, b[ft], acc1[ft], 0, 0, 0);
            }
        }
    }
#undef ISSUE

    // denominator partials: reduce over lq (lanes ln, ln+16, ln+32, ln+48)
    lp0 += __shfl_xor(lp0, 16); lp0 += __shfl_xor(lp0, 32);
    lp1 += __shfl_xor(lp1, 16); lp1 += __shfl_xor(lp1, 32);
    if (l < 16) {
        lpPart[(size_t)s * N + R0 + ln]      = lp0;
        lpPart[(size_t)s * N + R0 + 16 + ln] = lp1;
    }

    // numerator partials: C layout col=ln, row=4*lq+reg (per 16-row tile)
    float* __restrict__ pp = part + ((size_t)s * N + R0) * OUT_F;
#pragma unroll
    for (int ft = 0; ft < 8; ++ft)
#pragma unroll
        for (int r = 0; r < 4; ++r) {
            pp[(size_t)(4 * lq + r) * OUT_F + 16 * ft + ln]        = acc0[ft][r];
            pp[(size_t)(16 + 4 * lq + r) * OUT_F + 16 * ft + ln]   = acc1[ft][r];
        }
}

// ---------------- Kernel 3: combine segments, normalize, ELU ----------------
__global__ __launch_bounds__(256) void k_comb(const float* __restrict__ part,
                                              const float* __restrict__ lpPart,
                                              float* __restrict__ out) {
    const int idx = blockIdx.x * 256 + threadIdx.x;   // float4 id, N*OUT_F/4 total
    const int row = idx >> 5;                          // 32 float4 per row
    const int c4  = idx & 31;

    float lsum = 0.f;
#pragma unroll
    for (int s = 0; s < SEG; ++s) lsum += lpPart[(size_t)s * N + row];

    f32x4 v = {0.f, 0.f, 0.f, 0.f};
#pragma unroll
    for (int s = 0; s < SEG; ++s)
        v += *(const f32x4*)(part + ((size_t)s * N + row) * OUT_F + c4 * 4);

    const float inv = 1.0f / lsum;
    f32x4 r;
#pragma unroll
    for (int k = 0; k < 4; ++k) {
        float hp = v[k] * inv;
        r[k] = hp > 0.f ? hp : expm1f(hp);
    }
    *(f32x4*)(out + (size_t)row * OUT_F + c4 * 4) = r;
}

extern "C" void kernel_launch(void* const* d_in, const int* in_sizes, int n_in,
                              void* d_out, int out_size, void* d_ws, size_t ws_size,
                              hipStream_t stream) {
    const float* h   = (const float*)d_in[0];
    const int*   adj = (const int*)d_in[1];
    const float* W   = (const float*)d_in[2];
    const float* a   = (const float*)d_in[3];
    float* out = (float*)d_out;

    f16*   WT  = (f16*)d_ws;                         // 64 KB
    f16*   WhT = (f16*)((char*)d_ws + (1 << 16));    // 2 MB
    float* src = (float*)((char*)WhT + (size_t)OUT_F * N * sizeof(f16));
    float* dst = src + N;
    float* lpP = dst + N;                                  // SEG*N*4 = 256 KB (ends < 8 MB)
    float* part = (float*)((char*)d_ws + (8u << 20));      // SEG*N*OUT_F*4 = 32 MB

    k_prep<<<128, 256, 0, stream>>>(W, WT);
    k_wh<<<N / 32, 256, 0, stream>>>(h, WT, a, WhT, src, dst);
    k_attn<<<(N / 128) * SEG, 256, 0, stream>>>(adj, WhT, src, dst, part, lpP);
    k_comb<<<(N * OUT_F / 4) / 256, 256, 0, stream>>>(part, lpP, out);
}